// Round 14
// baseline (422.297 us; speedup 1.0000x reference)
//
#include <hip/hip_runtime.h>
#include <math.h>

#define N_NODES 10000
#define N_EDGES 320000
#define ZDIM    256
#define NPAD    10240          // 80 * 128 = 40 * 256
#define PAD_J   240.0f         // padded cols contribute exp2(0)=1 to row sums
#define HCAP    (1u<<19)
#define HMASK   (HCAP-1u)
#define TWO_LOG2E 2.8853900817779268f   // z1 pre-scale: exp(dot/0.5) = exp2(dot*2log2e)
#define LOG2E     1.4426950408889634f
#define NJT 40                 // 256-wide j-tiles
#define PSTRIDE ((size_t)NJT*NPAD)

typedef _Float16 half8 __attribute__((ext_vector_type(8)));
typedef _Float16 half4 __attribute__((ext_vector_type(4)));
typedef float f32x4 __attribute__((ext_vector_type(4)));

__device__ __forceinline__ float wave_red_sum64(float v){
#pragma unroll
  for(int off=1; off<64; off<<=1) v += __shfl_xor(v, off, 64);
  return v;
}

// ---------- fused: L2 normalize both arrays + diagonal S_ii, one pass ----------
__global__ void k_l2norm_diag(const float* __restrict__ pz1, const float* __restrict__ pz2,
                              _Float16* __restrict__ z1h, _Float16* __restrict__ z2h,
                              float* __restrict__ sii){
  int r = blockIdx.x;
  int t = threadIdx.x;
  float v1 = (r < N_NODES) ? pz1[(size_t)r*ZDIM + t] : 0.f;
  float v2 = (r < N_NODES) ? pz2[(size_t)r*ZDIM + t] : 0.f;
  float s1 = wave_red_sum64(v1*v1);
  float s2 = wave_red_sum64(v2*v2);
  float s12= wave_red_sum64(v1*v2);
  __shared__ float red[3][4];
  int lane = t & 63, wid = t >> 6;
  if(lane==0){ red[0][wid]=s1; red[1][wid]=s2; red[2][wid]=s12; }
  __syncthreads();
  float t1 = red[0][0]+red[0][1]+red[0][2]+red[0][3];
  float t2 = red[1][0]+red[1][1]+red[1][2]+red[1][3];
  float t12= red[2][0]+red[2][1]+red[2][2]+red[2][3];
  float sc1 = TWO_LOG2E/fmaxf(sqrtf(t1), 1e-12f);
  float sc2 = 1.f/fmaxf(sqrtf(t2), 1e-12f);
  z1h[(size_t)r*ZDIM + t] = (_Float16)(v1*sc1);
  z2h[(size_t)r*ZDIM + t] = (_Float16)(v2*sc2);
  if(t==0) sii[r] = t12*sc1*sc2;
}

// ---------- fused edge pass: src-degree, dst-degree, duplicate hash (EMPTY=0, stores key+1) ----------
__global__ void k_edge_pre(const int* __restrict__ src, const int* __restrict__ dst,
                           int* __restrict__ deg, int* __restrict__ cnt,
                           unsigned* __restrict__ hkey, unsigned* __restrict__ hcnt){
  int e = blockIdx.x*blockDim.x + threadIdx.x;
  if(e >= N_EDGES) return;
  int s = src[e], d = dst[e];
  atomicAdd(&deg[s], 1);
  atomicAdd(&cnt[d], 1);
  unsigned key = (unsigned)s*10000u + (unsigned)d + 1u;   // +1 so 0 == empty
  unsigned slot = (key * 2654435761u) & HMASK;
  while(true){
    unsigned old = atomicCAS(&hkey[slot], 0u, key);
    if(old==0u || old==key){ atomicAdd(&hcnt[slot], 1u); break; }
    slot = (slot+1) & HMASK;
  }
}
__global__ void k_inv_nb(const int* __restrict__ deg, float* __restrict__ inv_nb){
  int i = blockIdx.x*blockDim.x + threadIdx.x;
  if(i < NPAD) inv_nb[i] = (i < N_NODES) ? 1.f/sqrtf((float)deg[i] + 1.f) : 0.f;
}

// ---------- MFMA fp16 streaming stats: 128x256 tile, 8 waves (2x4) ----------
// R14: __launch_bounds__(512,2) — LDS caps at 2 blocks/CU anyway; R13's (512,4)
// starved the register allocator (VGPR=64) and spilled ~95 MB to scratch (WRITE_SIZE).
__launch_bounds__(512, 2)
__global__ void k_stats_mfma(const _Float16* __restrict__ z1h, const _Float16* __restrict__ z2h,
                             const float* __restrict__ inv_nb, float* __restrict__ parts){
  __shared__ _Float16 As[128*64];    // 16 KB per k-step
  __shared__ _Float16 Bs[256*64];    // 32 KB per k-step
  __shared__ float sred[4][3][128];  // 6 KB wc-combine
  const int bid = blockIdx.x;
  const int xcd = bid & 7, c = bid >> 3;
  const int ib = c / 5, jj = c - ib*5;   // ib<80, jj<5
  const int jt = xcd*5 + jj;             // 0..39
  const int tid  = threadIdx.x;
  const int lane = tid & 63, w = tid >> 6;
  const int wr = w >> 2, wc = w & 3;     // 2 x 4 wave grid
  const int l15 = lane & 15, l4 = lane >> 4;
  const int i0 = ib * 128;
  const int n0 = jt * 256;

  f32x4 acc[4][4];
#pragma unroll
  for(int a=0;a<4;a++)
#pragma unroll
    for(int b=0;b<4;b++) acc[a][b] = (f32x4){0.f,0.f,0.f,0.f};

  for(int kc=0; kc<ZDIM; kc+=64){
    __syncthreads();                       // prev k-step's ds_reads done
#pragma unroll
    for(int q=0;q<2;q++){                  // A: 1024 slots, 2/thread
      int s = tid + q*512;
      int row = s >> 3;
      int cg  = (s & 7) ^ (row & 7);       // inverse swizzle on source
      __builtin_amdgcn_global_load_lds(
        (const __attribute__((address_space(1))) unsigned*)(z1h + (size_t)(i0+row)*ZDIM + kc + cg*8),
        (__attribute__((address_space(3))) unsigned*)(As + (size_t)s*8),
        16, 0, 0);
    }
#pragma unroll
    for(int q=0;q<4;q++){                  // B: 2048 slots, 4/thread
      int s = tid + q*512;
      int row = s >> 3;
      int cg  = (s & 7) ^ (row & 7);
      __builtin_amdgcn_global_load_lds(
        (const __attribute__((address_space(1))) unsigned*)(z2h + (size_t)(n0+row)*ZDIM + kc + cg*8),
        (__attribute__((address_space(3))) unsigned*)(Bs + (size_t)s*8),
        16, 0, 0);
    }
    __syncthreads();                       // staging complete
#pragma unroll
    for(int ksl=0; ksl<2; ++ksl){
      half8 af[4], bf[4];
#pragma unroll
      for(int mf=0; mf<4; ++mf){
        int r = wr*64 + mf*16 + l15;       // 0..127
        af[mf] = *(const half8*)((const char*)As + r*128 + (((ksl*4 + l4) ^ (r&7))<<4));
      }
#pragma unroll
      for(int nf=0; nf<4; ++nf){
        int r = wc*64 + nf*16 + l15;       // 0..255
        bf[nf] = *(const half8*)((const char*)Bs + r*128 + (((ksl*4 + l4) ^ (r&7))<<4));
      }
#pragma unroll
      for(int mf=0; mf<4; ++mf)
#pragma unroll
        for(int nf=0; nf<4; ++nf)
          acc[mf][nf] = __builtin_amdgcn_mfma_f32_16x16x32_f16(af[mf], bf[nf], acc[mf][nf], 0, 0, 0);
    }
  }

  // epilogue: e = exp2(acc) (z1 pre-scaled), per-row d/t1/t2
  float inbv[4];
#pragma unroll
  for(int nf=0;nf<4;nf++) inbv[nf] = inv_nb[n0 + wc*64 + nf*16 + l15];

  float dacc[4][4], t1a[4][4], t2a[4][4];
#pragma unroll
  for(int mf=0; mf<4; ++mf)
#pragma unroll
    for(int rg=0; rg<4; ++rg){ dacc[mf][rg]=0.f; t1a[mf][rg]=0.f; t2a[mf][rg]=0.f; }

#pragma unroll
  for(int mf=0; mf<4; ++mf)
#pragma unroll
    for(int nf=0; nf<4; ++nf){
      float inb = inbv[nf], inb2 = inb*inb;
#pragma unroll
      for(int rg=0; rg<4; ++rg){
        float e = exp2f(acc[mf][nf][rg]);
        dacc[mf][rg] += e;
        t1a[mf][rg] = fmaf(e, inb, t1a[mf][rg]);
        t2a[mf][rg] = fmaf(e*e, inb2, t2a[mf][rg]);
      }
    }

#pragma unroll
  for(int mf=0; mf<4; ++mf)
#pragma unroll
    for(int rg=0; rg<4; ++rg){
      float d = dacc[mf][rg], t1 = t1a[mf][rg], t2 = t2a[mf][rg];
#pragma unroll
      for(int off=1; off<16; off<<=1){
        d  += __shfl_xor(d,  off, 64);
        t1 += __shfl_xor(t1, off, 64);
        t2 += __shfl_xor(t2, off, 64);
      }
      if(l15==0){
        int il = wr*64 + mf*16 + l4*4 + rg;   // 0..127
        sred[wc][0][il] = d;
        sred[wc][1][il] = t1;
        sred[wc][2][il] = t2;
      }
    }
  __syncthreads();
  if(tid < 128){
#pragma unroll
    for(int s=0;s<3;s++){
      float v = (sred[0][s][tid] + sred[1][s][tid]) + (sred[2][s][tid] + sred[3][s][tid]);
      parts[(size_t)s*PSTRIDE + (size_t)jt*NPAD + i0 + tid] = v;
    }
  }
}

// ---------- fused: reduce partials over jt + per-i stats + fp64 moment accumulation ----------
__global__ void k_redfin(const float* __restrict__ parts, const float* __restrict__ inv_nb,
                         const float* __restrict__ sii,
                         float* __restrict__ dsum, float* __restrict__ t1s, float* __restrict__ t2s,
                         double* __restrict__ scalacc){
  int i = blockIdx.x*256 + threadIdx.x;
  float a=0.f, b=0.f, c=0.f;
  if(i < NPAD){
    for(int j=0;j<NJT;j++){
      size_t o = (size_t)j*NPAD + i;
      a += parts[o];
      b += parts[PSTRIDE + o];
      c += parts[2*PSTRIDE + o];
    }
    dsum[i]=a; t1s[i]=b; t2s[i]=c;
  }
  double A=0,B=0,S1=0,S2=0,Snb=0,Snb2=0;
  if(i < N_NODES){
    float d   = a - PAD_J;
    float inb = inv_nb[i];
    A = (double)(b*inb/d);
    B = (double)((c*inb*inb)/(d*d));
    float eii = exp2f(sii[i]);
    float ci  = fabsf(eii/d - 1.f)*inb;
    S1 = (double)ci; S2 = (double)ci*(double)ci;
    Snb = (double)inb; Snb2 = (double)inb*(double)inb;
  }
  __shared__ double red[256];
  double vals[6]={A,B,S1,S2,Snb,Snb2};
  int tid = threadIdx.x;
  for(int v=0;v<6;v++){
    red[tid]=vals[v]; __syncthreads();
    for(int off=128;off;off>>=1){ if(tid<off) red[tid]+=red[tid+off]; __syncthreads(); }
    if(tid==0) atomicAdd(&scalacc[v], red[0]);
    __syncthreads();
  }
}

// ---------- tiny: moments -> scal ----------
__global__ void k_scal(const double* __restrict__ scalacc, float* __restrict__ scal){
  if(threadIdx.x==0){
    double M = (double)N_NODES*(double)N_NODES;
    double mean  = scalacc[0]/M;
    double var   = (scalacc[1] - scalacc[0]*scalacc[0]/M)/(M-1.0);
    double sp5   = scalacc[2]*scalacc[4];
    double mean5 = sp5/M;
    double var5  = (scalacc[3]*scalacc[5] - sp5*sp5/M)/(M-1.0);
    scal[0]=(float)mean;  scal[1]=(float)(1.0/sqrt(var));
    scal[2]=(float)mean5; scal[3]=(float)(1.0/sqrt(var5));
  }
}

// ---------- per-edge weight (8 lanes/edge) + fused weighted dst-degree ----------
__global__ void k_edge_w(const int* __restrict__ src, const int* __restrict__ dst,
                         const _Float16* __restrict__ z1h, const _Float16* __restrict__ z2h,
                         const float* __restrict__ dsum, const float* __restrict__ inv_nb,
                         const float* __restrict__ sii, const float* __restrict__ scal,
                         const unsigned* __restrict__ hkey, const unsigned* __restrict__ hcnt,
                         float* __restrict__ ew, float* __restrict__ degw){
  int gt = blockIdx.x*blockDim.x + threadIdx.x;
  int e = gt >> 3, l = gt & 7;
  if(e >= N_EDGES) return;
  int s = src[e], d = dst[e];
  const _Float16* ps = z1h + (size_t)s*ZDIM + l*32;
  const _Float16* pd = z2h + (size_t)d*ZDIM + l*32;
  half8 x0 = *(const half8*)(ps);
  half8 x1 = *(const half8*)(ps + 8);
  half8 x2 = *(const half8*)(ps + 16);
  half8 x3 = *(const half8*)(ps + 24);
  half8 y0 = *(const half8*)(pd);
  half8 y1 = *(const half8*)(pd + 8);
  half8 y2 = *(const half8*)(pd + 16);
  half8 y3 = *(const half8*)(pd + 24);
  float dot = 0.f;
#pragma unroll
  for(int q=0;q<8;q++) dot = fmaf((float)x0[q], (float)y0[q], dot);
#pragma unroll
  for(int q=0;q<8;q++) dot = fmaf((float)x1[q], (float)y1[q], dot);
#pragma unroll
  for(int q=0;q<8;q++) dot = fmaf((float)x2[q], (float)y2[q], dot);
#pragma unroll
  for(int q=0;q<8;q++) dot = fmaf((float)x3[q], (float)y3[q], dot);
#pragma unroll
  for(int off=1; off<8; off<<=1) dot += __shfl_xor(dot, off, 64);
  if(l==0){
    float ds = dsum[s] - PAD_J;
    float P  = exp2f(dot)/ds * inv_nb[s]*inv_nb[d];
    float z  = (P - scal[0])*scal[1];
    float p12 = 1.f/(1.f + exp2f(-z*LOG2E));
    float eii = exp2f(sii[s]);
    float c5  = fabsf(eii/ds - 1.f)*inv_nb[s]*inv_nb[d];
    float z5  = (c5 - scal[2])*scal[3];
    float p5  = 1.f/(1.f + exp2f(-z5*LOG2E));
    unsigned key  = (unsigned)s*10000u + (unsigned)d + 1u;
    unsigned slot = (key*2654435761u) & HMASK;
    while(hkey[slot] != key) slot = (slot+1) & HMASK;
    float wv = 0.5f*(p5 + p12) * (float)hcnt[slot];
    ew[e] = wv;
    atomicAdd(&degw[d], wv);
  }
}

// ---------- cast fp32 -> fp16 with zero row padding ----------
__global__ void k_cast_pad(const float* __restrict__ A, _Float16* __restrict__ Ah, int M, int K){
  size_t t = (size_t)blockIdx.x*256 + threadIdx.x;
  size_t total = (size_t)NPAD*K/8;
  if(t >= total) return;
  size_t base = t*8;
  int row = (int)(base / (size_t)K);
  half8 o;
  if(row < M){
    float4 v0 = *(const float4*)(A + base);
    float4 v1 = *(const float4*)(A + base + 4);
    o[0]=(_Float16)v0.x; o[1]=(_Float16)v0.y; o[2]=(_Float16)v0.z; o[3]=(_Float16)v0.w;
    o[4]=(_Float16)v1.x; o[5]=(_Float16)v1.y; o[6]=(_Float16)v1.z; o[7]=(_Float16)v1.w;
  } else {
#pragma unroll
    for(int q=0;q<8;q++) o[q]=(_Float16)0.f;
  }
  *(half8*)(Ah + base) = o;
}

// ---------- transpose + cast: WT[n][k] = (fp16)W[k][n] ----------
__global__ void k_transpose_h(const float* __restrict__ W, _Float16* __restrict__ WT, int K, int N){
  __shared__ float t[32][33];
  int bx = blockIdx.x*32, by = blockIdx.y*32;
  int tx = threadIdx.x, ty = threadIdx.y;       // 32 x 8
  for(int r=ty; r<32; r+=8) t[r][tx] = W[(size_t)(by+r)*N + bx+tx];
  __syncthreads();
  for(int r=ty; r<32; r+=8) WT[(size_t)(bx+r)*K + by+tx] = (_Float16)t[tx][r];
}

// ---------- MFMA fp16 GEMM, 64x64 tiles, 2-phase gl_lds pipeline (round-6 proven) ----------
__launch_bounds__(256, 4)
__global__ void k_gemm_h(const _Float16* __restrict__ Ah, const _Float16* __restrict__ BT,
                         _Float16* __restrict__ C, int K, int Nc){
  __shared__ _Float16 As[2][64*64];   // 2 x 8 KB
  __shared__ _Float16 Bs[2][64*64];   // 2 x 8 KB
  const int tid  = threadIdx.x;
  const int lane = tid & 63, w = tid >> 6;
  const int wr = w >> 1, wc = w & 1;
  const int l15 = lane & 15, l4 = lane >> 4;
  const int i0 = blockIdx.x * 64;
  const int n0 = blockIdx.y * 64;

  f32x4 acc[2][2];
#pragma unroll
  for(int a=0;a<2;a++)
#pragma unroll
    for(int b=0;b<2;b++) acc[a][b] = (f32x4){0.f,0.f,0.f,0.f};

  auto stage = [&](int buf, int kc){
#pragma unroll
    for(int q=0;q<2;q++){
      int s = w*128 + q*64 + lane;
      int row = s >> 3;
      int cg  = (s & 7) ^ (row & 7);
      __builtin_amdgcn_global_load_lds(
        (const __attribute__((address_space(1))) unsigned*)(Ah + (size_t)(i0+row)*K + kc + cg*8),
        (__attribute__((address_space(3))) unsigned*)(&As[buf][(w*128 + q*64)*8]),
        16, 0, 0);
      __builtin_amdgcn_global_load_lds(
        (const __attribute__((address_space(1))) unsigned*)(BT + (size_t)(n0+row)*K + kc + cg*8),
        (__attribute__((address_space(3))) unsigned*)(&Bs[buf][(w*128 + q*64)*8]),
        16, 0, 0);
    }
  };
  auto compute = [&](int buf){
#pragma unroll
    for(int ksl=0; ksl<2; ++ksl){
      half8 af[2], bf[2];
#pragma unroll
      for(int mf=0; mf<2; ++mf){
        int r = wr*32 + mf*16 + l15;
        af[mf] = *(const half8*)((const char*)As[buf] + r*128 + (((ksl*4 + l4) ^ (r&7))<<4));
      }
#pragma unroll
      for(int nf=0; nf<2; ++nf){
        int r = wc*32 + nf*16 + l15;
        bf[nf] = *(const half8*)((const char*)Bs[buf] + r*128 + (((ksl*4 + l4) ^ (r&7))<<4));
      }
#pragma unroll
      for(int mf=0; mf<2; ++mf)
#pragma unroll
        for(int nf=0; nf<2; ++nf)
          acc[mf][nf] = __builtin_amdgcn_mfma_f32_16x16x32_f16(af[mf], bf[nf], acc[mf][nf], 0, 0, 0);
    }
  };

  const int nk = K >> 6;
  stage(0, 0);
  asm volatile("s_waitcnt vmcnt(0)" ::: "memory");
  __builtin_amdgcn_s_barrier();
  for(int kc64=0; kc64<nk-1; ++kc64){
    stage((kc64+1)&1, (kc64+1)*64);
    compute(kc64&1);
    asm volatile("s_waitcnt vmcnt(0)" ::: "memory");
    __builtin_amdgcn_s_barrier();
  }
  compute((nk-1)&1);

#pragma unroll
  for(int mf=0; mf<2; ++mf)
#pragma unroll
    for(int nf=0; nf<2; ++nf){
      int col = n0 + wc*32 + nf*16 + l15;
#pragma unroll
      for(int rg=0; rg<4; ++rg){
        int rowi = i0 + wr*32 + mf*16 + l4*4 + rg;
        C[(size_t)rowi*Nc + col] = (_Float16)acc[mf][nf][rg];
      }
    }
}

// ---------- CSR by dst ----------
__global__ void k_scan(const int* __restrict__ cnt, int* __restrict__ rowptr){
  __shared__ int part[1024];
  const int PER = 10;
  int tid = threadIdx.x;
  int base = tid*PER;
  int loc[PER];
  int s=0;
#pragma unroll
  for(int q=0;q<PER;q++){ int idx=base+q; int v=(idx<N_NODES)?cnt[idx]:0; loc[q]=v; s+=v; }
  part[tid]=s; __syncthreads();
  for(int off=1; off<1024; off<<=1){
    int v = (tid>=off) ? part[tid-off] : 0;
    __syncthreads();
    part[tid] += v;
    __syncthreads();
  }
  int run = (tid>0) ? part[tid-1] : 0;
#pragma unroll
  for(int q=0;q<PER;q++){ int idx=base+q; if(idx<N_NODES) rowptr[idx]=run; run+=loc[q]; }
  if(tid==1023) rowptr[N_NODES]=part[1023];
}
// fill CSR with pre-combined weights: scsr = src, wcsr = rsqrt(1+degw[src])*ew
__global__ void k_fill2(const int* __restrict__ dst, const int* __restrict__ src,
                        const float* __restrict__ ew, const float* __restrict__ degw,
                        const int* __restrict__ rowptr, int* __restrict__ fill,
                        int* __restrict__ scsr, float* __restrict__ wcsr){
  int e = blockIdx.x*blockDim.x + threadIdx.x;
  if(e >= N_EDGES) return;
  int d = dst[e];
  int pos = atomicAdd(&fill[d], 1);
  int idx = rowptr[d] + pos;
  int s = src[e];
  scsr[idx] = s;
  wcsr[idx] = ew[e]*rsqrtf(1.f + degw[s]);
}

// ---------- GCN aggregation: half8 gathers (16B/lane), multi-vertex blocks, 8x unroll ----------
template<int F, typename OutT>
__global__ void k_agg2(const _Float16* __restrict__ hw, const float* __restrict__ bias,
                       const int* __restrict__ rowptr, const int* __restrict__ scsr,
                       const float* __restrict__ wcsr, const float* __restrict__ degw,
                       OutT* __restrict__ out){
  const int NT = F/8;                         // threads per vertex (64 or 32)
  const int v = blockIdx.x*(256/NT) + threadIdx.x/NT;
  const int tid = threadIdx.x & (NT-1);
  if(v >= N_NODES) return;
  const half8* hp = (const half8*)hw;         // row stride = NT half8s
  float dv = rsqrtf(1.f + degw[v]);
  half8 hs = hp[(size_t)v*NT + tid];
  float a[8];
#pragma unroll
  for(int j=0;j<8;j++) a[j] = dv*(float)hs[j];
  int b = rowptr[v], e = rowptr[v+1];
  int t = b;
  for(; t+8<=e; t+=8){
    int   sv[8]; float wv[8]; half8 hv[8];
#pragma unroll
    for(int q=0;q<8;q++){ sv[q]=scsr[t+q]; wv[q]=wcsr[t+q]; }
#pragma unroll
    for(int q=0;q<8;q++) hv[q] = hp[(size_t)sv[q]*NT + tid];
#pragma unroll
    for(int q=0;q<8;q++)
#pragma unroll
      for(int j=0;j<8;j++) a[j] = fmaf(wv[q], (float)hv[q][j], a[j]);
  }
  for(; t<e; ++t){
    int s=scsr[t]; float wq=wcsr[t];
    half8 h = hp[(size_t)s*NT + tid];
#pragma unroll
    for(int j=0;j<8;j++) a[j] = fmaf(wq, (float)h[j], a[j]);
  }
  int f0 = tid*8;
  float4 b0 = *(const float4*)(bias + f0);
  float4 b1 = *(const float4*)(bias + f0 + 4);
  float r[8];
  r[0]=fmaxf(dv*a[0]+b0.x,0.f); r[1]=fmaxf(dv*a[1]+b0.y,0.f);
  r[2]=fmaxf(dv*a[2]+b0.z,0.f); r[3]=fmaxf(dv*a[3]+b0.w,0.f);
  r[4]=fmaxf(dv*a[4]+b1.x,0.f); r[5]=fmaxf(dv*a[5]+b1.y,0.f);
  r[6]=fmaxf(dv*a[6]+b1.z,0.f); r[7]=fmaxf(dv*a[7]+b1.w,0.f);
  if constexpr (sizeof(OutT)==2){
    half8 o;
#pragma unroll
    for(int j=0;j<8;j++) o[j]=(_Float16)r[j];
    *(half8*)(out + (size_t)v*F + f0) = o;
  } else {
    *(float4*)(out + (size_t)v*F + f0    ) = make_float4(r[0],r[1],r[2],r[3]);
    *(float4*)(out + (size_t)v*F + f0 + 4) = make_float4(r[4],r[5],r[6],r[7]);
  }
}

extern "C" void kernel_launch(void* const* d_in, const int* in_sizes, int n_in,
                              void* d_out, int out_size, void* d_ws, size_t ws_size,
                              hipStream_t stream){
  const float* x   = (const float*)d_in[0];
  const float* pz1 = (const float*)d_in[1];
  const float* pz2 = (const float*)d_in[2];
  const float* W0  = (const float*)d_in[3];
  const float* b0  = (const float*)d_in[4];
  const float* W1  = (const float*)d_in[5];
  const float* b1  = (const float*)d_in[6];
  const int*   ei  = (const int*)d_in[7];
  const int* src = ei;
  const int* dst = ei + N_EDGES;
  float* out = (float*)d_out;

  char* ws = (char*)d_ws;
  size_t off = 0;
  auto alloc = [&](size_t bytes)->char*{
    char* p = ws + off;
    off += (bytes + 255) & ~(size_t)255;
    return p;
  };

  _Float16* z1h  = (_Float16*)alloc((size_t)NPAD*ZDIM*2);   // reused as hw1h after k_edge_w
  _Float16* z2h  = (_Float16*)alloc((size_t)NPAD*ZDIM*2);
  _Float16* xh   = (_Float16*)alloc((size_t)NPAD*512*2);
  _Float16* hw0h = (_Float16*)alloc((size_t)NPAD*512*2);
  _Float16* h1h  = (_Float16*)alloc((size_t)NPAD*512*2);
  _Float16* W0T  = (_Float16*)alloc((size_t)512*512*2);
  _Float16* W1T  = (_Float16*)alloc((size_t)256*512*2);
  float* parts   = (float*)alloc(3*PSTRIDE*4);              // 4.9 MB
  float* ew      = (float*)alloc((size_t)N_EDGES*4);
  float* dsum    = (float*)alloc(NPAD*4);
  float* t1s     = (float*)alloc(NPAD*4);
  float* t2s     = (float*)alloc(NPAD*4);
  float* inv_nb  = (float*)alloc(NPAD*4);
  float* sii     = (float*)alloc(NPAD*4);
  float* scal    = (float*)alloc(256);
  // zero-init group: deg|cnt|fill|degw|scalacc contiguous -> 1 memset
  int* deg       = (int*)alloc(NPAD*4);
  int* cnt       = (int*)alloc(NPAD*4);
  int* fill      = (int*)alloc(NPAD*4);
  float* degw    = (float*)alloc(NPAD*4);
  double* scalacc= (double*)alloc(256);
  int* rowptr    = (int*)alloc((NPAD+1)*4);
  int* scsr      = (int*)alloc((size_t)N_EDGES*4);
  float* wcsr    = (float*)alloc((size_t)N_EDGES*4);
  // zero-init group 2: hkey|hcnt contiguous (EMPTY==0 via key+1) -> 1 memset
  unsigned* hkey = (unsigned*)alloc((size_t)HCAP*4);
  unsigned* hcnt = (unsigned*)alloc((size_t)HCAP*4);
  _Float16* hw1h = z1h;     // [NPAD,256] fp16, z1h dead after k_edge_w

  hipMemsetAsync(deg,  0, (size_t)4*NPAD*4 + 256, stream);  // deg,cnt,fill,degw,scalacc
  hipMemsetAsync(hkey, 0, (size_t)2*HCAP*4, stream);        // hkey,hcnt

  const int EB = (N_EDGES+255)/256;

  // similarity pipeline (z1 pre-scaled by 2*log2e; sii fused into l2norm pass)
  k_l2norm_diag<<<NPAD, 256, 0, stream>>>(pz1, pz2, z1h, z2h, sii);
  k_edge_pre<<<EB, 256, 0, stream>>>(src, dst, deg, cnt, hkey, hcnt);
  k_inv_nb<<<(NPAD+255)/256, 256, 0, stream>>>(deg, inv_nb);
  k_stats_mfma<<<80*40, 512, 0, stream>>>(z1h, z2h, inv_nb, parts);
  k_redfin<<<(NPAD+255)/256, 256, 0, stream>>>(parts, inv_nb, sii, dsum, t1s, t2s, scalacc);
  k_scal<<<1, 64, 0, stream>>>(scalacc, scal);
  k_edge_w<<<(N_EDGES*8)/256, 256, 0, stream>>>(src, dst, z1h, z2h, dsum, inv_nb, sii, scal, hkey, hcnt, ew, degw);

  // GCN prep
  k_cast_pad<<<(int)(((size_t)NPAD*512/8 + 255)/256), 256, 0, stream>>>(x, xh, N_NODES, 512);
  k_transpose_h<<<dim3(16,16), dim3(32,8), 0, stream>>>(W0, W0T, 512, 512);
  k_transpose_h<<<dim3(8,16),  dim3(32,8), 0, stream>>>(W1, W1T, 512, 256);

  k_scan<<<1, 1024, 0, stream>>>(cnt, rowptr);
  k_fill2<<<EB, 256, 0, stream>>>(dst, src, ew, degw, rowptr, fill, scsr, wcsr);

  // layer 1: hw0h = fp16(xh @ W0); h1h = fp16(relu(agg(hw0h) + b0))
  k_gemm_h<<<dim3(160, 8), 256, 0, stream>>>(xh, W0T, hw0h, 512, 512);
  k_agg2<512,_Float16><<<2500, 256, 0, stream>>>(hw0h, b0, rowptr, scsr, wcsr, degw, h1h);
  // layer 2: hw1h = fp16(h1h @ W1); out = relu(agg(hw1h) + b1)
  k_gemm_h<<<dim3(160, 4), 256, 0, stream>>>(h1h, W1T, hw1h, 512, 256);
  k_agg2<256,float><<<1250, 256, 0, stream>>>(hw1h, b1, rowptr, scsr, wcsr, degw, out);

  (void)in_sizes; (void)n_in; (void)out_size; (void)ws_size;
}

// Round 15
// 397.060 us; speedup vs baseline: 1.0636x; 1.0636x over previous
//
#include <hip/hip_runtime.h>
#include <math.h>

#define N_NODES 10000
#define N_EDGES 320000
#define ZDIM    256
#define NPAD    10240          // 80 * 128
#define PAD_J   240.0f         // padded cols contribute exp2(0)=1 to row sums
#define HCAP    (1u<<19)
#define HMASK   (HCAP-1u)
#define TWO_LOG2E 2.8853900817779268f   // z1 pre-scale: exp(dot/0.5) = exp2(dot*2log2e)
#define LOG2E     1.4426950408889634f
#define NJB 80                 // 128-wide j-tiles (80 divisible by 8 -> no dead blocks)
#define PSTRIDE ((size_t)NJB*NPAD)

typedef _Float16 half8 __attribute__((ext_vector_type(8)));
typedef _Float16 half4 __attribute__((ext_vector_type(4)));
typedef float f32x4 __attribute__((ext_vector_type(4)));

__device__ __forceinline__ float wave_red_sum64(float v){
#pragma unroll
  for(int off=1; off<64; off<<=1) v += __shfl_xor(v, off, 64);
  return v;
}

// ---------- fused: L2 normalize both arrays + diagonal S_ii, one pass ----------
__global__ void k_l2norm_diag(const float* __restrict__ pz1, const float* __restrict__ pz2,
                              _Float16* __restrict__ z1h, _Float16* __restrict__ z2h,
                              float* __restrict__ sii){
  int r = blockIdx.x;
  int t = threadIdx.x;
  float v1 = (r < N_NODES) ? pz1[(size_t)r*ZDIM + t] : 0.f;
  float v2 = (r < N_NODES) ? pz2[(size_t)r*ZDIM + t] : 0.f;
  float s1 = wave_red_sum64(v1*v1);
  float s2 = wave_red_sum64(v2*v2);
  float s12= wave_red_sum64(v1*v2);
  __shared__ float red[3][4];
  int lane = t & 63, wid = t >> 6;
  if(lane==0){ red[0][wid]=s1; red[1][wid]=s2; red[2][wid]=s12; }
  __syncthreads();
  float t1 = red[0][0]+red[0][1]+red[0][2]+red[0][3];
  float t2 = red[1][0]+red[1][1]+red[1][2]+red[1][3];
  float t12= red[2][0]+red[2][1]+red[2][2]+red[2][3];
  float sc1 = TWO_LOG2E/fmaxf(sqrtf(t1), 1e-12f);
  float sc2 = 1.f/fmaxf(sqrtf(t2), 1e-12f);
  z1h[(size_t)r*ZDIM + t] = (_Float16)(v1*sc1);
  z2h[(size_t)r*ZDIM + t] = (_Float16)(v2*sc2);
  if(t==0) sii[r] = t12*sc1*sc2;
}

// ---------- fused edge pass: src-degree, dst-degree, duplicate hash (EMPTY=0, stores key+1) ----------
__global__ void k_edge_pre(const int* __restrict__ src, const int* __restrict__ dst,
                           int* __restrict__ deg, int* __restrict__ cnt,
                           unsigned* __restrict__ hkey, unsigned* __restrict__ hcnt){
  int e = blockIdx.x*blockDim.x + threadIdx.x;
  if(e >= N_EDGES) return;
  int s = src[e], d = dst[e];
  atomicAdd(&deg[s], 1);
  atomicAdd(&cnt[d], 1);
  unsigned key = (unsigned)s*10000u + (unsigned)d + 1u;   // +1 so 0 == empty
  unsigned slot = (key * 2654435761u) & HMASK;
  while(true){
    unsigned old = atomicCAS(&hkey[slot], 0u, key);
    if(old==0u || old==key){ atomicAdd(&hcnt[slot], 1u); break; }
    slot = (slot+1) & HMASK;
  }
}
__global__ void k_inv_nb(const int* __restrict__ deg, float* __restrict__ inv_nb){
  int i = blockIdx.x*blockDim.x + threadIdx.x;
  if(i < NPAD) inv_nb[i] = (i < N_NODES) ? 1.f/sqrtf((float)deg[i] + 1.f) : 0.f;
}

// ---------- MFMA fp16 streaming stats: R12-proven 128x128 body (113.6 us reproducible) ----------
// single-buffer gl_lds staging, 2 syncthreads/k-step, 4 blocks/CU, XCD-chunked 80x80 grid
// (6400 blocks, 80%8==0 -> every block valid). 256-wide tiles refuted (R13 spill / R14 occupancy).
__launch_bounds__(256, 4)
__global__ void k_stats_mfma(const _Float16* __restrict__ z1h, const _Float16* __restrict__ z2h,
                             const float* __restrict__ inv_nb, float* __restrict__ parts){
  __shared__ _Float16 As[128*64];    // 16 KB per k-step
  __shared__ _Float16 Bs[128*64];    // 16 KB
  __shared__ float sred[2][3][128];  // 3 KB wc-combine
  const int bid = blockIdx.x;
  const int xcd = bid & 7, c = bid >> 3;
  const int ib = c / 10, jj = c - ib*10;   // ib<80, jj<10
  const int jb = xcd*10 + jj;              // 0..79
  const int tid  = threadIdx.x;
  const int lane = tid & 63, w = tid >> 6;
  const int wr = w >> 1, wc = w & 1;
  const int l15 = lane & 15, l4 = lane >> 4;
  const int i0 = ib * 128;
  const int n0 = jb * 128;

  f32x4 acc[4][4];
#pragma unroll
  for(int a=0;a<4;a++)
#pragma unroll
    for(int b=0;b<4;b++) acc[a][b] = (f32x4){0.f,0.f,0.f,0.f};

  for(int kc=0; kc<ZDIM; kc+=64){
    __syncthreads();                       // prev k-step's ds_reads done
#pragma unroll
    for(int q=0;q<4;q++){
      int s = w*256 + q*64 + lane;         // linear 16B slot
      int row = s >> 3;
      int cg  = (s & 7) ^ (row & 7);       // inverse swizzle on source
      __builtin_amdgcn_global_load_lds(
        (const __attribute__((address_space(1))) unsigned*)(z1h + (size_t)(i0+row)*ZDIM + kc + cg*8),
        (__attribute__((address_space(3))) unsigned*)(As + (size_t)(w*256 + q*64)*8),
        16, 0, 0);
      __builtin_amdgcn_global_load_lds(
        (const __attribute__((address_space(1))) unsigned*)(z2h + (size_t)(n0+row)*ZDIM + kc + cg*8),
        (__attribute__((address_space(3))) unsigned*)(Bs + (size_t)(w*256 + q*64)*8),
        16, 0, 0);
    }
    __syncthreads();                       // staging complete
#pragma unroll
    for(int ksl=0; ksl<2; ++ksl){
      half8 af[4], bf[4];
#pragma unroll
      for(int mf=0; mf<4; ++mf){
        int r = wr*64 + mf*16 + l15;
        af[mf] = *(const half8*)((const char*)As + r*128 + (((ksl*4 + l4) ^ (r&7))<<4));
      }
#pragma unroll
      for(int nf=0; nf<4; ++nf){
        int r = wc*64 + nf*16 + l15;
        bf[nf] = *(const half8*)((const char*)Bs + r*128 + (((ksl*4 + l4) ^ (r&7))<<4));
      }
#pragma unroll
      for(int mf=0; mf<4; ++mf)
#pragma unroll
        for(int nf=0; nf<4; ++nf)
          acc[mf][nf] = __builtin_amdgcn_mfma_f32_16x16x32_f16(af[mf], bf[nf], acc[mf][nf], 0, 0, 0);
    }
  }

  // epilogue: e = exp2(acc) (z1 pre-scaled), per-row d/t1/t2
  float inbv[4];
#pragma unroll
  for(int nf=0;nf<4;nf++) inbv[nf] = inv_nb[n0 + wc*64 + nf*16 + l15];

  float dacc[4][4], t1a[4][4], t2a[4][4];
#pragma unroll
  for(int mf=0; mf<4; ++mf)
#pragma unroll
    for(int rg=0; rg<4; ++rg){ dacc[mf][rg]=0.f; t1a[mf][rg]=0.f; t2a[mf][rg]=0.f; }

#pragma unroll
  for(int mf=0; mf<4; ++mf)
#pragma unroll
    for(int nf=0; nf<4; ++nf){
      float inb = inbv[nf], inb2 = inb*inb;
#pragma unroll
      for(int rg=0; rg<4; ++rg){
        float e = exp2f(acc[mf][nf][rg]);
        dacc[mf][rg] += e;
        t1a[mf][rg] = fmaf(e, inb, t1a[mf][rg]);
        t2a[mf][rg] = fmaf(e*e, inb2, t2a[mf][rg]);
      }
    }

#pragma unroll
  for(int mf=0; mf<4; ++mf)
#pragma unroll
    for(int rg=0; rg<4; ++rg){
      float d = dacc[mf][rg], t1 = t1a[mf][rg], t2 = t2a[mf][rg];
#pragma unroll
      for(int off=1; off<16; off<<=1){
        d  += __shfl_xor(d,  off, 64);
        t1 += __shfl_xor(t1, off, 64);
        t2 += __shfl_xor(t2, off, 64);
      }
      if(l15==0){
        int il = wr*64 + mf*16 + l4*4 + rg;
        sred[wc][0][il] = d;
        sred[wc][1][il] = t1;
        sred[wc][2][il] = t2;
      }
    }
  __syncthreads();
  if(tid < 128){
#pragma unroll
    for(int s=0;s<3;s++){
      float v = sred[0][s][tid] + sred[1][s][tid];
      parts[(size_t)s*PSTRIDE + (size_t)jb*NPAD + i0 + tid] = v;
    }
  }
}

// ---------- fused: reduce partials over jb + per-i stats + fp64 moment accumulation ----------
__global__ void k_redfin(const float* __restrict__ parts, const float* __restrict__ inv_nb,
                         const float* __restrict__ sii,
                         float* __restrict__ dsum, float* __restrict__ t1s, float* __restrict__ t2s,
                         double* __restrict__ scalacc){
  int i = blockIdx.x*256 + threadIdx.x;
  float a=0.f, b=0.f, c=0.f;
  if(i < NPAD){
    for(int j=0;j<NJB;j++){
      size_t o = (size_t)j*NPAD + i;
      a += parts[o];
      b += parts[PSTRIDE + o];
      c += parts[2*PSTRIDE + o];
    }
    dsum[i]=a; t1s[i]=b; t2s[i]=c;
  }
  double A=0,B=0,S1=0,S2=0,Snb=0,Snb2=0;
  if(i < N_NODES){
    float d   = a - PAD_J;
    float inb = inv_nb[i];
    A = (double)(b*inb/d);
    B = (double)((c*inb*inb)/(d*d));
    float eii = exp2f(sii[i]);
    float ci  = fabsf(eii/d - 1.f)*inb;
    S1 = (double)ci; S2 = (double)ci*(double)ci;
    Snb = (double)inb; Snb2 = (double)inb*(double)inb;
  }
  __shared__ double red[256];
  double vals[6]={A,B,S1,S2,Snb,Snb2};
  int tid = threadIdx.x;
  for(int v=0;v<6;v++){
    red[tid]=vals[v]; __syncthreads();
    for(int off=128;off;off>>=1){ if(tid<off) red[tid]+=red[tid+off]; __syncthreads(); }
    if(tid==0) atomicAdd(&scalacc[v], red[0]);
    __syncthreads();
  }
}

// ---------- tiny: moments -> scal ----------
__global__ void k_scal(const double* __restrict__ scalacc, float* __restrict__ scal){
  if(threadIdx.x==0){
    double M = (double)N_NODES*(double)N_NODES;
    double mean  = scalacc[0]/M;
    double var   = (scalacc[1] - scalacc[0]*scalacc[0]/M)/(M-1.0);
    double sp5   = scalacc[2]*scalacc[4];
    double mean5 = sp5/M;
    double var5  = (scalacc[3]*scalacc[5] - sp5*sp5/M)/(M-1.0);
    scal[0]=(float)mean;  scal[1]=(float)(1.0/sqrt(var));
    scal[2]=(float)mean5; scal[3]=(float)(1.0/sqrt(var5));
  }
}

// ---------- per-edge weight (8 lanes/edge) + fused weighted dst-degree ----------
__global__ void k_edge_w(const int* __restrict__ src, const int* __restrict__ dst,
                         const _Float16* __restrict__ z1h, const _Float16* __restrict__ z2h,
                         const float* __restrict__ dsum, const float* __restrict__ inv_nb,
                         const float* __restrict__ sii, const float* __restrict__ scal,
                         const unsigned* __restrict__ hkey, const unsigned* __restrict__ hcnt,
                         float* __restrict__ ew, float* __restrict__ degw){
  int gt = blockIdx.x*blockDim.x + threadIdx.x;
  int e = gt >> 3, l = gt & 7;
  if(e >= N_EDGES) return;
  int s = src[e], d = dst[e];
  const _Float16* ps = z1h + (size_t)s*ZDIM + l*32;
  const _Float16* pd = z2h + (size_t)d*ZDIM + l*32;
  half8 x0 = *(const half8*)(ps);
  half8 x1 = *(const half8*)(ps + 8);
  half8 x2 = *(const half8*)(ps + 16);
  half8 x3 = *(const half8*)(ps + 24);
  half8 y0 = *(const half8*)(pd);
  half8 y1 = *(const half8*)(pd + 8);
  half8 y2 = *(const half8*)(pd + 16);
  half8 y3 = *(const half8*)(pd + 24);
  float dot = 0.f;
#pragma unroll
  for(int q=0;q<8;q++) dot = fmaf((float)x0[q], (float)y0[q], dot);
#pragma unroll
  for(int q=0;q<8;q++) dot = fmaf((float)x1[q], (float)y1[q], dot);
#pragma unroll
  for(int q=0;q<8;q++) dot = fmaf((float)x2[q], (float)y2[q], dot);
#pragma unroll
  for(int q=0;q<8;q++) dot = fmaf((float)x3[q], (float)y3[q], dot);
#pragma unroll
  for(int off=1; off<8; off<<=1) dot += __shfl_xor(dot, off, 64);
  if(l==0){
    float ds = dsum[s] - PAD_J;
    float P  = exp2f(dot)/ds * inv_nb[s]*inv_nb[d];
    float z  = (P - scal[0])*scal[1];
    float p12 = 1.f/(1.f + exp2f(-z*LOG2E));
    float eii = exp2f(sii[s]);
    float c5  = fabsf(eii/ds - 1.f)*inv_nb[s]*inv_nb[d];
    float z5  = (c5 - scal[2])*scal[3];
    float p5  = 1.f/(1.f + exp2f(-z5*LOG2E));
    unsigned key  = (unsigned)s*10000u + (unsigned)d + 1u;
    unsigned slot = (key*2654435761u) & HMASK;
    while(hkey[slot] != key) slot = (slot+1) & HMASK;
    float wv = 0.5f*(p5 + p12) * (float)hcnt[slot];
    ew[e] = wv;
    atomicAdd(&degw[d], wv);
  }
}

// ---------- cast fp32 -> fp16 with zero row padding ----------
__global__ void k_cast_pad(const float* __restrict__ A, _Float16* __restrict__ Ah, int M, int K){
  size_t t = (size_t)blockIdx.x*256 + threadIdx.x;
  size_t total = (size_t)NPAD*K/8;
  if(t >= total) return;
  size_t base = t*8;
  int row = (int)(base / (size_t)K);
  half8 o;
  if(row < M){
    float4 v0 = *(const float4*)(A + base);
    float4 v1 = *(const float4*)(A + base + 4);
    o[0]=(_Float16)v0.x; o[1]=(_Float16)v0.y; o[2]=(_Float16)v0.z; o[3]=(_Float16)v0.w;
    o[4]=(_Float16)v1.x; o[5]=(_Float16)v1.y; o[6]=(_Float16)v1.z; o[7]=(_Float16)v1.w;
  } else {
#pragma unroll
    for(int q=0;q<8;q++) o[q]=(_Float16)0.f;
  }
  *(half8*)(Ah + base) = o;
}

// ---------- transpose + cast: WT[n][k] = (fp16)W[k][n] ----------
__global__ void k_transpose_h(const float* __restrict__ W, _Float16* __restrict__ WT, int K, int N){
  __shared__ float t[32][33];
  int bx = blockIdx.x*32, by = blockIdx.y*32;
  int tx = threadIdx.x, ty = threadIdx.y;       // 32 x 8
  for(int r=ty; r<32; r+=8) t[r][tx] = W[(size_t)(by+r)*N + bx+tx];
  __syncthreads();
  for(int r=ty; r<32; r+=8) WT[(size_t)(bx+r)*K + by+tx] = (_Float16)t[tx][r];
}

// ---------- MFMA fp16 GEMM, 64x64 tiles, 2-phase gl_lds pipeline (round-6 proven) ----------
__launch_bounds__(256, 4)
__global__ void k_gemm_h(const _Float16* __restrict__ Ah, const _Float16* __restrict__ BT,
                         _Float16* __restrict__ C, int K, int Nc){
  __shared__ _Float16 As[2][64*64];   // 2 x 8 KB
  __shared__ _Float16 Bs[2][64*64];   // 2 x 8 KB
  const int tid  = threadIdx.x;
  const int lane = tid & 63, w = tid >> 6;
  const int wr = w >> 1, wc = w & 1;
  const int l15 = lane & 15, l4 = lane >> 4;
  const int i0 = blockIdx.x * 64;
  const int n0 = blockIdx.y * 64;

  f32x4 acc[2][2];
#pragma unroll
  for(int a=0;a<2;a++)
#pragma unroll
    for(int b=0;b<2;b++) acc[a][b] = (f32x4){0.f,0.f,0.f,0.f};

  auto stage = [&](int buf, int kc){
#pragma unroll
    for(int q=0;q<2;q++){
      int s = w*128 + q*64 + lane;
      int row = s >> 3;
      int cg  = (s & 7) ^ (row & 7);
      __builtin_amdgcn_global_load_lds(
        (const __attribute__((address_space(1))) unsigned*)(Ah + (size_t)(i0+row)*K + kc + cg*8),
        (__attribute__((address_space(3))) unsigned*)(&As[buf][(w*128 + q*64)*8]),
        16, 0, 0);
      __builtin_amdgcn_global_load_lds(
        (const __attribute__((address_space(1))) unsigned*)(BT + (size_t)(n0+row)*K + kc + cg*8),
        (__attribute__((address_space(3))) unsigned*)(&Bs[buf][(w*128 + q*64)*8]),
        16, 0, 0);
    }
  };
  auto compute = [&](int buf){
#pragma unroll
    for(int ksl=0; ksl<2; ++ksl){
      half8 af[2], bf[2];
#pragma unroll
      for(int mf=0; mf<2; ++mf){
        int r = wr*32 + mf*16 + l15;
        af[mf] = *(const half8*)((const char*)As[buf] + r*128 + (((ksl*4 + l4) ^ (r&7))<<4));
      }
#pragma unroll
      for(int nf=0; nf<2; ++nf){
        int r = wc*32 + nf*16 + l15;
        bf[nf] = *(const half8*)((const char*)Bs[buf] + r*128 + (((ksl*4 + l4) ^ (r&7))<<4));
      }
#pragma unroll
      for(int mf=0; mf<2; ++mf)
#pragma unroll
        for(int nf=0; nf<2; ++nf)
          acc[mf][nf] = __builtin_amdgcn_mfma_f32_16x16x32_f16(af[mf], bf[nf], acc[mf][nf], 0, 0, 0);
    }
  };

  const int nk = K >> 6;
  stage(0, 0);
  asm volatile("s_waitcnt vmcnt(0)" ::: "memory");
  __builtin_amdgcn_s_barrier();
  for(int kc64=0; kc64<nk-1; ++kc64){
    stage((kc64+1)&1, (kc64+1)*64);
    compute(kc64&1);
    asm volatile("s_waitcnt vmcnt(0)" ::: "memory");
    __builtin_amdgcn_s_barrier();
  }
  compute((nk-1)&1);

#pragma unroll
  for(int mf=0; mf<2; ++mf)
#pragma unroll
    for(int nf=0; nf<2; ++nf){
      int col = n0 + wc*32 + nf*16 + l15;
#pragma unroll
      for(int rg=0; rg<4; ++rg){
        int rowi = i0 + wr*32 + mf*16 + l4*4 + rg;
        C[(size_t)rowi*Nc + col] = (_Float16)acc[mf][nf][rg];
      }
    }
}

// ---------- CSR by dst ----------
__global__ void k_scan(const int* __restrict__ cnt, int* __restrict__ rowptr){
  __shared__ int part[1024];
  const int PER = 10;
  int tid = threadIdx.x;
  int base = tid*PER;
  int loc[PER];
  int s=0;
#pragma unroll
  for(int q=0;q<PER;q++){ int idx=base+q; int v=(idx<N_NODES)?cnt[idx]:0; loc[q]=v; s+=v; }
  part[tid]=s; __syncthreads();
  for(int off=1; off<1024; off<<=1){
    int v = (tid>=off) ? part[tid-off] : 0;
    __syncthreads();
    part[tid] += v;
    __syncthreads();
  }
  int run = (tid>0) ? part[tid-1] : 0;
#pragma unroll
  for(int q=0;q<PER;q++){ int idx=base+q; if(idx<N_NODES) rowptr[idx]=run; run+=loc[q]; }
  if(tid==1023) rowptr[N_NODES]=part[1023];
}
// fill CSR with pre-combined weights: scsr = src, wcsr = rsqrt(1+degw[src])*ew
__global__ void k_fill2(const int* __restrict__ dst, const int* __restrict__ src,
                        const float* __restrict__ ew, const float* __restrict__ degw,
                        const int* __restrict__ rowptr, int* __restrict__ fill,
                        int* __restrict__ scsr, float* __restrict__ wcsr){
  int e = blockIdx.x*blockDim.x + threadIdx.x;
  if(e >= N_EDGES) return;
  int d = dst[e];
  int pos = atomicAdd(&fill[d], 1);
  int idx = rowptr[d] + pos;
  int s = src[e];
  scsr[idx] = s;
  wcsr[idx] = ew[e]*rsqrtf(1.f + degw[s]);
}

// ---------- GCN aggregation: half8 gathers (16B/lane), multi-vertex blocks, 8x unroll ----------
template<int F, typename OutT>
__global__ void k_agg2(const _Float16* __restrict__ hw, const float* __restrict__ bias,
                       const int* __restrict__ rowptr, const int* __restrict__ scsr,
                       const float* __restrict__ wcsr, const float* __restrict__ degw,
                       OutT* __restrict__ out){
  const int NT = F/8;                         // threads per vertex (64 or 32)
  const int v = blockIdx.x*(256/NT) + threadIdx.x/NT;
  const int tid = threadIdx.x & (NT-1);
  if(v >= N_NODES) return;
  const half8* hp = (const half8*)hw;         // row stride = NT half8s
  float dv = rsqrtf(1.f + degw[v]);
  half8 hs = hp[(size_t)v*NT + tid];
  float a[8];
#pragma unroll
  for(int j=0;j<8;j++) a[j] = dv*(float)hs[j];
  int b = rowptr[v], e = rowptr[v+1];
  int t = b;
  for(; t+8<=e; t+=8){
    int   sv[8]; float wv[8]; half8 hv[8];
#pragma unroll
    for(int q=0;q<8;q++){ sv[q]=scsr[t+q]; wv[q]=wcsr[t+q]; }
#pragma unroll
    for(int q=0;q<8;q++) hv[q] = hp[(size_t)sv[q]*NT + tid];
#pragma unroll
    for(int q=0;q<8;q++)
#pragma unroll
      for(int j=0;j<8;j++) a[j] = fmaf(wv[q], (float)hv[q][j], a[j]);
  }
  for(; t<e; ++t){
    int s=scsr[t]; float wq=wcsr[t];
    half8 h = hp[(size_t)s*NT + tid];
#pragma unroll
    for(int j=0;j<8;j++) a[j] = fmaf(wq, (float)h[j], a[j]);
  }
  int f0 = tid*8;
  float4 b0 = *(const float4*)(bias + f0);
  float4 b1 = *(const float4*)(bias + f0 + 4);
  float r[8];
  r[0]=fmaxf(dv*a[0]+b0.x,0.f); r[1]=fmaxf(dv*a[1]+b0.y,0.f);
  r[2]=fmaxf(dv*a[2]+b0.z,0.f); r[3]=fmaxf(dv*a[3]+b0.w,0.f);
  r[4]=fmaxf(dv*a[4]+b1.x,0.f); r[5]=fmaxf(dv*a[5]+b1.y,0.f);
  r[6]=fmaxf(dv*a[6]+b1.z,0.f); r[7]=fmaxf(dv*a[7]+b1.w,0.f);
  if constexpr (sizeof(OutT)==2){
    half8 o;
#pragma unroll
    for(int j=0;j<8;j++) o[j]=(_Float16)r[j];
    *(half8*)(out + (size_t)v*F + f0) = o;
  } else {
    *(float4*)(out + (size_t)v*F + f0    ) = make_float4(r[0],r[1],r[2],r[3]);
    *(float4*)(out + (size_t)v*F + f0 + 4) = make_float4(r[4],r[5],r[6],r[7]);
  }
}

extern "C" void kernel_launch(void* const* d_in, const int* in_sizes, int n_in,
                              void* d_out, int out_size, void* d_ws, size_t ws_size,
                              hipStream_t stream){
  const float* x   = (const float*)d_in[0];
  const float* pz1 = (const float*)d_in[1];
  const float* pz2 = (const float*)d_in[2];
  const float* W0  = (const float*)d_in[3];
  const float* b0  = (const float*)d_in[4];
  const float* W1  = (const float*)d_in[5];
  const float* b1  = (const float*)d_in[6];
  const int*   ei  = (const int*)d_in[7];
  const int* src = ei;
  const int* dst = ei + N_EDGES;
  float* out = (float*)d_out;

  char* ws = (char*)d_ws;
  size_t off = 0;
  auto alloc = [&](size_t bytes)->char*{
    char* p = ws + off;
    off += (bytes + 255) & ~(size_t)255;
    return p;
  };

  _Float16* z1h  = (_Float16*)alloc((size_t)NPAD*ZDIM*2);   // reused as hw1h after k_edge_w
  _Float16* z2h  = (_Float16*)alloc((size_t)NPAD*ZDIM*2);
  _Float16* xh   = (_Float16*)alloc((size_t)NPAD*512*2);
  _Float16* hw0h = (_Float16*)alloc((size_t)NPAD*512*2);
  _Float16* h1h  = (_Float16*)alloc((size_t)NPAD*512*2);
  _Float16* W0T  = (_Float16*)alloc((size_t)512*512*2);
  _Float16* W1T  = (_Float16*)alloc((size_t)256*512*2);
  float* parts   = (float*)alloc(3*PSTRIDE*4);              // 9.8 MB
  float* ew      = (float*)alloc((size_t)N_EDGES*4);
  float* dsum    = (float*)alloc(NPAD*4);
  float* t1s     = (float*)alloc(NPAD*4);
  float* t2s     = (float*)alloc(NPAD*4);
  float* inv_nb  = (float*)alloc(NPAD*4);
  float* sii     = (float*)alloc(NPAD*4);
  float* scal    = (float*)alloc(256);
  // zero-init group: deg|cnt|fill|degw|scalacc contiguous -> 1 memset
  int* deg       = (int*)alloc(NPAD*4);
  int* cnt       = (int*)alloc(NPAD*4);
  int* fill      = (int*)alloc(NPAD*4);
  float* degw    = (float*)alloc(NPAD*4);
  double* scalacc= (double*)alloc(256);
  int* rowptr    = (int*)alloc((NPAD+1)*4);
  int* scsr      = (int*)alloc((size_t)N_EDGES*4);
  float* wcsr    = (float*)alloc((size_t)N_EDGES*4);
  // zero-init group 2: hkey|hcnt contiguous (EMPTY==0 via key+1) -> 1 memset
  unsigned* hkey = (unsigned*)alloc((size_t)HCAP*4);
  unsigned* hcnt = (unsigned*)alloc((size_t)HCAP*4);
  _Float16* hw1h = z1h;     // [NPAD,256] fp16, z1h dead after k_edge_w

  hipMemsetAsync(deg,  0, (size_t)4*NPAD*4 + 256, stream);  // deg,cnt,fill,degw,scalacc
  hipMemsetAsync(hkey, 0, (size_t)2*HCAP*4, stream);        // hkey,hcnt

  const int EB = (N_EDGES+255)/256;

  // similarity pipeline (z1 pre-scaled by 2*log2e; sii fused into l2norm pass)
  k_l2norm_diag<<<NPAD, 256, 0, stream>>>(pz1, pz2, z1h, z2h, sii);
  k_edge_pre<<<EB, 256, 0, stream>>>(src, dst, deg, cnt, hkey, hcnt);
  k_inv_nb<<<(NPAD+255)/256, 256, 0, stream>>>(deg, inv_nb);
  k_stats_mfma<<<80*80, 256, 0, stream>>>(z1h, z2h, inv_nb, parts);
  k_redfin<<<(NPAD+255)/256, 256, 0, stream>>>(parts, inv_nb, sii, dsum, t1s, t2s, scalacc);
  k_scal<<<1, 64, 0, stream>>>(scalacc, scal);
  k_edge_w<<<(N_EDGES*8)/256, 256, 0, stream>>>(src, dst, z1h, z2h, dsum, inv_nb, sii, scal, hkey, hcnt, ew, degw);

  // GCN prep
  k_cast_pad<<<(int)(((size_t)NPAD*512/8 + 255)/256), 256, 0, stream>>>(x, xh, N_NODES, 512);
  k_transpose_h<<<dim3(16,16), dim3(32,8), 0, stream>>>(W0, W0T, 512, 512);
  k_transpose_h<<<dim3(8,16),  dim3(32,8), 0, stream>>>(W1, W1T, 512, 256);

  k_scan<<<1, 1024, 0, stream>>>(cnt, rowptr);
  k_fill2<<<EB, 256, 0, stream>>>(dst, src, ew, degw, rowptr, fill, scsr, wcsr);

  // layer 1: hw0h = fp16(xh @ W0); h1h = fp16(relu(agg(hw0h) + b0))
  k_gemm_h<<<dim3(160, 8), 256, 0, stream>>>(xh, W0T, hw0h, 512, 512);
  k_agg2<512,_Float16><<<2500, 256, 0, stream>>>(hw0h, b0, rowptr, scsr, wcsr, degw, h1h);
  // layer 2: hw1h = fp16(h1h @ W1); out = relu(agg(hw1h) + b1)
  k_gemm_h<<<dim3(160, 4), 256, 0, stream>>>(h1h, W1T, hw1h, 512, 256);
  k_agg2<256,float><<<1250, 256, 0, stream>>>(hw1h, b1, rowptr, scsr, wcsr, degw, out);

  (void)in_sizes; (void)n_in; (void)out_size; (void)ws_size;
}